// Round 12
// baseline (792.528 us; speedup 1.0000x reference)
//
#include <hip/hip_runtime.h>

typedef __attribute__((ext_vector_type(8))) short short8;
typedef __attribute__((ext_vector_type(4))) float f32x4;
typedef __attribute__((ext_vector_type(16))) float f32x16;
typedef __attribute__((ext_vector_type(4))) unsigned short u16x4;
typedef __attribute__((ext_vector_type(8))) unsigned short u16x8;

typedef __attribute__((address_space(3))) void lds_void;
typedef __attribute__((address_space(1))) void g_void;

#define GL16(g, l) __builtin_amdgcn_global_load_lds((g_void*)(g), (lds_void*)(l), 16, 0, 0)
#define EXP2F(x) __builtin_exp2f(x)

__device__ inline float b2f(unsigned short u) {
  union { unsigned u; float f; } v; v.u = ((unsigned)u) << 16; return v.f;
}
__device__ inline unsigned short f2b(float f) {
  union { float f; unsigned u; } v; v.f = f;
  unsigned r = v.u + 0x7FFFu + ((v.u >> 16) & 1u);
  return (unsigned short)(r >> 16);
}
__device__ inline unsigned short f2b_rne(float f) {
  unsigned u;
  asm("v_cvt_pk_bf16_f32 %0, %1, %2" : "=v"(u) : "v"(f), "v"(f));
  return (unsigned short)u;
}

// ---------- fp32 -> bf16 convert (vectorized) ----------
__global__ __launch_bounds__(256) void conv_f32_bf16(const float* __restrict__ in,
                                                     unsigned short* __restrict__ out, long n) {
  long i = ((long)blockIdx.x * 256 + threadIdx.x) * 4;
  if (i >= n) return;
  f32x4 v = *(const f32x4*)(in + i);
  u16x4 o;
  o[0] = f2b(v[0]); o[1] = f2b(v[1]); o[2] = f2b(v[2]); o[3] = f2b(v[3]);
  *(u16x4*)(out + i) = o;
}

// ---------- all 4 weight transposes in one launch: W (4096 x C) -> W^T bf16 (C x 4096) ----------
__global__ __launch_bounds__(256) void prep_weights(const float* __restrict__ Wq,
                                                    const float* __restrict__ Wk,
                                                    const float* __restrict__ Wv,
                                                    const float* __restrict__ Wo,
                                                    unsigned short* __restrict__ Wqkv,
                                                    unsigned short* __restrict__ Wot) {
  __shared__ unsigned short tile[32][33];
  int id = blockIdx.x;
  const float* src; unsigned short* dst; int C;
  if (id < 16384)      { src = Wq; dst = Wqkv;            C = 4096; }
  else if (id < 20480) { src = Wk; dst = Wqkv + 16777216; C = 1024; id -= 16384; }
  else if (id < 24576) { src = Wv; dst = Wqkv + 20971520; C = 1024; id -= 20480; }
  else                 { src = Wo; dst = Wot;             C = 4096; id -= 24576; }
  const int nbx = C >> 5;
  const int c0 = (id % nbx) * 32, r0 = (id / nbx) * 32;
  const int tx = threadIdx.x & 31, ty = threadIdx.x >> 5;
#pragma unroll
  for (int i = ty; i < 32; i += 8)
    tile[i][tx] = f2b(src[(long)(r0 + i) * C + c0 + tx]);
  __syncthreads();
#pragma unroll
  for (int i = ty; i < 32; i += 8)
    dst[(long)(c0 + i) * 4096 + r0 + tx] = tile[tx][i];
}

// ---------- bf16 transpose for V^T ----------
__global__ __launch_bounds__(256) void transpose_u16(const unsigned short* __restrict__ in,
                                                     unsigned short* __restrict__ out,
                                                     int R, int C, int ldin) {
  __shared__ unsigned short tile[32][33];
  int c0 = blockIdx.x * 32, r0 = blockIdx.y * 32;
  int tx = threadIdx.x & 31, ty = threadIdx.x >> 5;
#pragma unroll
  for (int i = ty; i < 32; i += 8)
    tile[i][tx] = in[(long)(r0 + i) * ldin + c0 + tx];
  __syncthreads();
#pragma unroll
  for (int i = ty; i < 32; i += 8)
    out[(long)(c0 + i) * R + r0 + tx] = tile[tx][i];
}

// ---------- bf16 GEMM, m97 structure, 128x128 tile, BK=64, 32x32x16 MFMA ----------
// MODE 0: fp32 C. MODE 2: bf16 C with fused RoPE on cols<5120 (qscale on cols<4096).
template <int MODE, int MINB>
__global__ __launch_bounds__(256, MINB) void gemm_m97(const unsigned short* __restrict__ A,
                                                      const unsigned short* __restrict__ Bt,
                                                      void* __restrict__ C,
                                                      const float* __restrict__ cosp,
                                                      const float* __restrict__ sinp,
                                                      int M, int N, int K) {
  __shared__ unsigned short As[128 * 64];
  __shared__ unsigned short Bs[128 * 64];
  const int tid = threadIdx.x;
  const int lane = tid & 63;
  const int wid = tid >> 6;
  const int wr = wid >> 1, wc = wid & 1;         // 2x2 waves, wave tile 64x64
  const int l31 = lane & 31, lh = lane >> 5;
  const int xr = l31 & 7;
  const int nbn = N >> 7;
  const int bm = blockIdx.x / nbn, bn = blockIdx.x % nbn; // natural order (L2-friendly)

  const long K2 = (long)K * 2;
  const int csw = ((tid & 7) ^ ((tid >> 3) & 7)) << 4;
  const char* gA = (const char*)A + ((long)bm * 128 + (tid >> 3)) * K2 + csw;
  const char* gB = (const char*)Bt + ((long)bn * 128 + (tid >> 3)) * K2 + csw;
  char* dA = (char*)As + tid * 16;
  char* dB = (char*)Bs + tid * 16;

  f32x16 acc[2][2];
#pragma unroll
  for (int m = 0; m < 2; m++)
#pragma unroll
    for (int n = 0; n < 2; n++)
#pragma unroll
      for (int i = 0; i < 16; i++) acc[m][n][i] = 0.f;

  const int offA0 = (wr * 64 + l31) * 128;
  const int offB0 = (wc * 64 + l31) * 128;

  const int NT = K >> 6;
  for (int t = 0; t < NT; ++t) {
    __syncthreads();
    const long ko = (long)t * 128;
    GL16(gA + ko, dA);
    GL16(gA + ko + 32 * K2, dA + 4096);
    GL16(gA + ko + 64 * K2, dA + 8192);
    GL16(gA + ko + 96 * K2, dA + 12288);
    GL16(gB + ko, dB);
    GL16(gB + ko + 32 * K2, dB + 4096);
    GL16(gB + ko + 64 * K2, dB + 8192);
    GL16(gB + ko + 96 * K2, dB + 12288);
    __syncthreads();
#pragma unroll
    for (int kk = 0; kk < 4; kk++) {
      const int co = (((kk * 2 + lh) ^ xr) << 4);
      short8 a0 = *(const short8*)((const char*)As + offA0 + co);
      short8 a1 = *(const short8*)((const char*)As + offA0 + 4096 + co);
      short8 b0 = *(const short8*)((const char*)Bs + offB0 + co);
      short8 b1 = *(const short8*)((const char*)Bs + offB0 + 4096 + co);
      acc[0][0] = __builtin_amdgcn_mfma_f32_32x32x16_bf16(a0, b0, acc[0][0], 0, 0, 0);
      acc[0][1] = __builtin_amdgcn_mfma_f32_32x32x16_bf16(a0, b1, acc[0][1], 0, 0, 0);
      acc[1][0] = __builtin_amdgcn_mfma_f32_32x32x16_bf16(a1, b0, acc[1][0], 0, 0, 0);
      acc[1][1] = __builtin_amdgcn_mfma_f32_32x32x16_bf16(a1, b1, acc[1][1], 0, 0, 0);
    }
  }

  const long crow0 = (long)bm * 128 + wr * 64 + 4 * lh;
  const int ccol0 = bn * 128 + wc * 64 + l31;
  const float qscale = 0.08838834764831845f * 1.44269504088896341f;
#pragma unroll
  for (int m = 0; m < 2; m++)
#pragma unroll
    for (int n = 0; n < 2; n++)
#pragma unroll
      for (int reg = 0; reg < 16; reg++) {
        long row = crow0 + m * 32 + (reg & 3) + 8 * (reg >> 2);
        int col = ccol0 + n * 32;
        float v = acc[m][n][reg];
        if (MODE == 0) {
          ((float*)C)[row * N + col] = v;
        } else {
          float other = __shfl_xor(v, 1, 64); // col pairs live in adjacent lanes
          float out = v;
          if (col < 5120) { // RoPE on Q and K columns
            int s = (int)(row & 2047);
            int ib = (col & 127) >> 1;
            float cc = cosp[s * 64 + ib], ss = sinp[s * 64 + ib];
            out = (col & 1) ? (other * ss + v * cc) : (v * cc - other * ss);
            if (col < 4096) out *= qscale; // 1/sqrt(128)*log2e folded into Q
          }
          ((unsigned short*)C)[row * N + col] = f2b_rne(out);
        }
      }
}

// ---------- flash attention, causal, GQA(4:1), XOR-swizzled LDS (40KB -> 4 blocks/CU) ----------
// Work-balanced: each block handles q-tiles (qt, nqt-1-qt) -> uniform nqt+1 kv-tiles.
__global__ __launch_bounds__(256, 4) void attn_kernel(const unsigned short* __restrict__ QKV,
                                                      const unsigned short* __restrict__ Vt,
                                                      unsigned short* __restrict__ O,
                                                      int S, int BS) {
  __shared__ unsigned short Ks[64 * 128];   // [kv][d], chunk^=(kv&7)
  __shared__ unsigned short Vs[128 * 64];   // [d][kv], chunk^=(d&7)
  __shared__ unsigned short Ps[4][16 * 64]; // per-wave [q][kv], chunk^=(q&7)
  const int tid = threadIdx.x, wave = tid >> 6, lane = tid & 63;
  const int lrow = lane & 15, kgrp = lane >> 4;
  const int nqt = S >> 6, nqt2 = nqt >> 1;
  int bid = blockIdx.x;
  const int qp = bid % nqt2; bid /= nqt2;
  const int h = bid & 31;
  const int b = bid >> 5;
  const int kh = h >> 2;
  const long rowbase = (long)b * S;

  const char* kg = (const char*)(QKV + rowbase * 6144 + 4096 + kh * 128)
                   + (tid >> 4) * 12288 + (((tid & 15) ^ ((tid >> 4) & 7)) * 16);
  const char* vg = (const char*)(Vt + (long)(kh * 128 + (tid >> 3)) * BS + rowbase)
                   + (((tid & 7) ^ ((tid >> 3) & 7)) * 16);
  char* lK = (char*)Ks + wave * 1024;
  char* lV = (char*)Vs + wave * 1024;

  for (int pass = 0; pass < 2; pass++) {
    const int qt = pass ? (nqt - 1 - qp) : qp;
    const int qbase = qt * 64;
    const int q0 = qbase + wave * 16;

    short8 qf[4];
    {
      const unsigned short* qpt = QKV + (rowbase + q0 + lrow) * 6144 + h * 128 + kgrp * 8;
#pragma unroll
      for (int dc = 0; dc < 4; dc++) qf[dc] = *(const short8*)(qpt + dc * 32);
    }
    f32x4 oacc[8];
#pragma unroll
    for (int dt = 0; dt < 8; dt++) oacc[dt] = (f32x4){0.f, 0.f, 0.f, 0.f};
    float mrun[4] = {-1e30f, -1e30f, -1e30f, -1e30f};
    float lrun[4] = {0.f, 0.f, 0.f, 0.f};

    const int kv_end = qbase + 64;
    for (int kv0 = 0; kv0 < kv_end; kv0 += 64) {
      __syncthreads();
#pragma unroll
      for (int p = 0; p < 4; p++)
        GL16(kg + (long)(kv0 + p * 16) * 12288, lK + p * 4096);
#pragma unroll
      for (int p = 0; p < 4; p++)
        GL16(vg + (long)kv0 * 2 + (long)p * 32 * BS * 2, lV + p * 4096);
      __syncthreads();

      f32x4 sc[4];
#pragma unroll
      for (int n = 0; n < 4; n++) {
        f32x4 s = (f32x4){0.f, 0.f, 0.f, 0.f};
#pragma unroll
        for (int dc = 0; dc < 4; dc++) {
          short8 kf = *(const short8*)(Ks + (n * 16 + lrow) * 128 + (((dc * 4 + kgrp) ^ (lrow & 7)) << 3));
          s = __builtin_amdgcn_mfma_f32_16x16x32_bf16(qf[dc], kf, s, 0, 0, 0);
        }
        sc[n] = s;
      }

      if (kv0 + 63 > q0) { // diagonal tile: causal mask
#pragma unroll
        for (int r = 0; r < 4; r++) {
          const int qg = q0 + kgrp * 4 + r;
#pragma unroll
          for (int n = 0; n < 4; n++) {
            int kgi = kv0 + n * 16 + lrow;
            if (kgi > qg) sc[n][r] = -1e30f;
          }
        }
      }

      float mx[4];
#pragma unroll
      for (int r = 0; r < 4; r++) {
        float m0 = fmaxf(fmaxf(sc[0][r], sc[1][r]), fmaxf(sc[2][r], sc[3][r]));
#pragma unroll
        for (int d = 1; d < 16; d <<= 1) m0 = fmaxf(m0, __shfl_xor(m0, d, 64));
        mx[r] = m0;
      }
      bool grow = false;
#pragma unroll
      for (int r = 0; r < 4; r++) grow = grow || (mx[r] > mrun[r] + 8.f);

      if (__all(!grow)) {
#pragma unroll
        for (int r = 0; r < 4; r++) {
          const int q = kgrp * 4 + r;
          const int pbase = q * 64;
          float psum = 0.f;
#pragma unroll
          for (int n = 0; n < 4; n++) {
            float pv = EXP2F(sc[n][r] - mrun[r]);
            psum += pv;
            int k = n * 16 + lrow;
            Ps[wave][pbase + ((((k >> 3) ^ (q & 7)) << 3) | (k & 7))] = f2b_rne(pv);
          }
          lrun[r] += psum;
        }
      } else {
#pragma unroll
        for (int r = 0; r < 4; r++) {
          const int q = kgrp * 4 + r;
          const int pbase = q * 64;
          float mnew = fmaxf(mrun[r], mx[r]);
          float corr = EXP2F(mrun[r] - mnew);
          mrun[r] = mnew;
          float psum = 0.f;
#pragma unroll
          for (int n = 0; n < 4; n++) {
            float pv = EXP2F(sc[n][r] - mnew);
            psum += pv;
            int k = n * 16 + lrow;
            Ps[wave][pbase + ((((k >> 3) ^ (q & 7)) << 3) | (k & 7))] = f2b_rne(pv);
          }
          lrun[r] = lrun[r] * corr + psum;
#pragma unroll
          for (int dt = 0; dt < 8; dt++) oacc[dt][r] *= corr;
        }
      }
      asm volatile("s_waitcnt lgkmcnt(0)" ::: "memory");
#pragma unroll
      for (int kc = 0; kc < 2; kc++) {
        short8 pa = *(const short8*)(&Ps[wave][lrow * 64 + (((kc * 4 + kgrp) ^ (lrow & 7)) << 3)]);
#pragma unroll
        for (int dt = 0; dt < 8; dt++) {
          short8 vb = *(const short8*)(Vs + (dt * 16 + lrow) * 64 + (((kc * 4 + kgrp) ^ (lrow & 7)) << 3));
          oacc[dt] = __builtin_amdgcn_mfma_f32_16x16x32_bf16(pa, vb, oacc[dt], 0, 0, 0);
        }
      }
    }

    float inv[4];
#pragma unroll
    for (int r = 0; r < 4; r++) {
      float l = lrun[r];
#pragma unroll
      for (int d = 1; d < 16; d <<= 1) l += __shfl_xor(l, d, 64);
      inv[r] = 1.f / l;
    }
    unsigned short* op = O + (rowbase + q0 + kgrp * 4) * 4096 + h * 128 + lrow;
#pragma unroll
    for (int dt = 0; dt < 8; dt++)
#pragma unroll
      for (int r = 0; r < 4; r++)
        op[(long)r * 4096 + dt * 16] = f2b_rne(oacc[dt][r] * inv[r]);
  }
}

extern "C" void kernel_launch(void* const* d_in, const int* in_sizes, int n_in,
                              void* d_out, int out_size, void* d_ws, size_t ws_size,
                              hipStream_t stream) {
  const float* x = (const float*)d_in[0];
  const float* cosp = (const float*)d_in[1];
  const float* sinp = (const float*)d_in[2];
  // d_in[3] = mask (causal 0/-1e9) -- applied analytically
  const float* Wq = (const float*)d_in[4];
  const float* Wk = (const float*)d_in[5];
  const float* Wv = (const float*)d_in[6];
  const float* Wo = (const float*)d_in[7];
  const int S = 2048;
  const long M = 4096; // B*S

  if (ws_size < 176160768ULL) return; // need 168 MiB scratch

  char* ws = (char*)d_ws;
  unsigned short* xb   = (unsigned short*)(ws);               // 32 MiB (aliased as AO later)
  unsigned short* Wqt  = (unsigned short*)(ws + 33554432);    // 48 MiB: Wqt|Wkt|Wvt = [6144][4096]
  unsigned short* Wot  = (unsigned short*)(ws + 83886080);    // 32 MiB
  unsigned short* QKVb = (unsigned short*)(ws + 117440512);   // 48 MiB [4096][6144]
  unsigned short* Vtg  = (unsigned short*)(ws + 167772160);   //  8 MiB [1024][4096]
  unsigned short* AO   = xb; // xb dead after QKV GEMM

  conv_f32_bf16<<<16384, 256, 0, stream>>>(x, xb, M * 4096);
  prep_weights<<<40960, 256, 0, stream>>>(Wq, Wk, Wv, Wo, Wqt, Wot);

  // fused QKV projection + RoPE epilogue: Bt = [Wqt|Wkt|Wvt], C = QKVb (4096 x 6144)
  gemm_m97<2, 3><<<1536, 256, 0, stream>>>(xb, Wqt, QKVb, cosp, sinp, 4096, 6144, 4096);
  // V^T for attention PV: from QKV cols 5120..6143 (un-roped)
  transpose_u16<<<dim3(32, 128), 256, 0, stream>>>(QKVb + 5120, Vtg, 4096, 1024, 6144);

  attn_kernel<<<1024, 256, 0, stream>>>(QKVb, Vtg, AO, S, 4096);

  gemm_m97<0, 4><<<1024, 256, 0, stream>>>(AO, Wot, d_out, nullptr, nullptr, 4096, 4096, 4096);
}

// Round 13
// 744.747 us; speedup vs baseline: 1.0642x; 1.0642x over previous
//
#include <hip/hip_runtime.h>

typedef __attribute__((ext_vector_type(8))) short short8;
typedef __attribute__((ext_vector_type(4))) float f32x4;
typedef __attribute__((ext_vector_type(16))) float f32x16;
typedef __attribute__((ext_vector_type(4))) unsigned short u16x4;
typedef __attribute__((ext_vector_type(8))) unsigned short u16x8;

typedef __attribute__((address_space(3))) void lds_void;
typedef __attribute__((address_space(1))) void g_void;

#define GL16(g, l) __builtin_amdgcn_global_load_lds((g_void*)(g), (lds_void*)(l), 16, 0, 0)
#define EXP2F(x) __builtin_exp2f(x)

__device__ inline float b2f(unsigned short u) {
  union { unsigned u; float f; } v; v.u = ((unsigned)u) << 16; return v.f;
}
__device__ inline unsigned short f2b(float f) {
  union { float f; unsigned u; } v; v.f = f;
  unsigned r = v.u + 0x7FFFu + ((v.u >> 16) & 1u);
  return (unsigned short)(r >> 16);
}
__device__ inline unsigned short f2b_rne(float f) {
  unsigned u;
  asm("v_cvt_pk_bf16_f32 %0, %1, %2" : "=v"(u) : "v"(f), "v"(f));
  return (unsigned short)u;
}

// ---------- fp32 -> bf16 convert (vectorized) ----------
__global__ __launch_bounds__(256) void conv_f32_bf16(const float* __restrict__ in,
                                                     unsigned short* __restrict__ out, long n) {
  long i = ((long)blockIdx.x * 256 + threadIdx.x) * 4;
  if (i >= n) return;
  f32x4 v = *(const f32x4*)(in + i);
  u16x4 o;
  o[0] = f2b(v[0]); o[1] = f2b(v[1]); o[2] = f2b(v[2]); o[3] = f2b(v[3]);
  *(u16x4*)(out + i) = o;
}

// ---------- all 4 weight transposes in one launch: W (4096 x C) -> W^T bf16 (C x 4096) ----------
__global__ __launch_bounds__(256) void prep_weights(const float* __restrict__ Wq,
                                                    const float* __restrict__ Wk,
                                                    const float* __restrict__ Wv,
                                                    const float* __restrict__ Wo,
                                                    unsigned short* __restrict__ Wqkv,
                                                    unsigned short* __restrict__ Wot) {
  __shared__ unsigned short tile[32][33];
  int id = blockIdx.x;
  const float* src; unsigned short* dst; int C;
  if (id < 16384)      { src = Wq; dst = Wqkv;            C = 4096; }
  else if (id < 20480) { src = Wk; dst = Wqkv + 16777216; C = 1024; id -= 16384; }
  else if (id < 24576) { src = Wv; dst = Wqkv + 20971520; C = 1024; id -= 20480; }
  else                 { src = Wo; dst = Wot;             C = 4096; id -= 24576; }
  const int nbx = C >> 5;
  const int c0 = (id % nbx) * 32, r0 = (id / nbx) * 32;
  const int tx = threadIdx.x & 31, ty = threadIdx.x >> 5;
#pragma unroll
  for (int i = ty; i < 32; i += 8)
    tile[i][tx] = f2b(src[(long)(r0 + i) * C + c0 + tx]);
  __syncthreads();
#pragma unroll
  for (int i = ty; i < 32; i += 8)
    dst[(long)(c0 + i) * 4096 + r0 + tx] = tile[tx][i];
}

// ---------- bf16 transpose for V^T ----------
__global__ __launch_bounds__(256) void transpose_u16(const unsigned short* __restrict__ in,
                                                     unsigned short* __restrict__ out,
                                                     int R, int C, int ldin) {
  __shared__ unsigned short tile[32][33];
  int c0 = blockIdx.x * 32, r0 = blockIdx.y * 32;
  int tx = threadIdx.x & 31, ty = threadIdx.x >> 5;
#pragma unroll
  for (int i = ty; i < 32; i += 8)
    tile[i][tx] = in[(long)(r0 + i) * ldin + c0 + tx];
  __syncthreads();
#pragma unroll
  for (int i = ty; i < 32; i += 8)
    out[(long)(c0 + i) * R + r0 + tx] = tile[tx][i];
}

// ---------- bf16 GEMM, m97 structure, 128x128 tile, BK=64, 32x32x16 MFMA ----------
// MODE 0: fp32 C. MODE 2: bf16 C with fused RoPE on cols<5120 (qscale on cols<4096).
template <int MODE, int MINB>
__global__ __launch_bounds__(256, MINB) void gemm_m97(const unsigned short* __restrict__ A,
                                                      const unsigned short* __restrict__ Bt,
                                                      void* __restrict__ C,
                                                      const float* __restrict__ cosp,
                                                      const float* __restrict__ sinp,
                                                      int M, int N, int K) {
  __shared__ unsigned short As[128 * 64];
  __shared__ unsigned short Bs[128 * 64];
  const int tid = threadIdx.x;
  const int lane = tid & 63;
  const int wid = tid >> 6;
  const int wr = wid >> 1, wc = wid & 1;         // 2x2 waves, wave tile 64x64
  const int l31 = lane & 31, lh = lane >> 5;
  const int xr = l31 & 7;
  const int nbn = N >> 7;
  const int bm = blockIdx.x / nbn, bn = blockIdx.x % nbn; // natural order (L2-friendly)

  const long K2 = (long)K * 2;
  const int csw = ((tid & 7) ^ ((tid >> 3) & 7)) << 4;
  const char* gA = (const char*)A + ((long)bm * 128 + (tid >> 3)) * K2 + csw;
  const char* gB = (const char*)Bt + ((long)bn * 128 + (tid >> 3)) * K2 + csw;
  char* dA = (char*)As + tid * 16;
  char* dB = (char*)Bs + tid * 16;

  f32x16 acc[2][2];
#pragma unroll
  for (int m = 0; m < 2; m++)
#pragma unroll
    for (int n = 0; n < 2; n++)
#pragma unroll
      for (int i = 0; i < 16; i++) acc[m][n][i] = 0.f;

  const int offA0 = (wr * 64 + l31) * 128;
  const int offB0 = (wc * 64 + l31) * 128;

  const int NT = K >> 6;
  for (int t = 0; t < NT; ++t) {
    __syncthreads();
    const long ko = (long)t * 128;
    GL16(gA + ko, dA);
    GL16(gA + ko + 32 * K2, dA + 4096);
    GL16(gA + ko + 64 * K2, dA + 8192);
    GL16(gA + ko + 96 * K2, dA + 12288);
    GL16(gB + ko, dB);
    GL16(gB + ko + 32 * K2, dB + 4096);
    GL16(gB + ko + 64 * K2, dB + 8192);
    GL16(gB + ko + 96 * K2, dB + 12288);
    __syncthreads();
#pragma unroll
    for (int kk = 0; kk < 4; kk++) {
      const int co = (((kk * 2 + lh) ^ xr) << 4);
      short8 a0 = *(const short8*)((const char*)As + offA0 + co);
      short8 a1 = *(const short8*)((const char*)As + offA0 + 4096 + co);
      short8 b0 = *(const short8*)((const char*)Bs + offB0 + co);
      short8 b1 = *(const short8*)((const char*)Bs + offB0 + 4096 + co);
      acc[0][0] = __builtin_amdgcn_mfma_f32_32x32x16_bf16(a0, b0, acc[0][0], 0, 0, 0);
      acc[0][1] = __builtin_amdgcn_mfma_f32_32x32x16_bf16(a0, b1, acc[0][1], 0, 0, 0);
      acc[1][0] = __builtin_amdgcn_mfma_f32_32x32x16_bf16(a1, b0, acc[1][0], 0, 0, 0);
      acc[1][1] = __builtin_amdgcn_mfma_f32_32x32x16_bf16(a1, b1, acc[1][1], 0, 0, 0);
    }
  }

  const long crow0 = (long)bm * 128 + wr * 64 + 4 * lh;
  const int ccol0 = bn * 128 + wc * 64 + l31;
  const float qscale = 0.08838834764831845f * 1.44269504088896341f;
#pragma unroll
  for (int m = 0; m < 2; m++)
#pragma unroll
    for (int n = 0; n < 2; n++)
#pragma unroll
      for (int reg = 0; reg < 16; reg++) {
        long row = crow0 + m * 32 + (reg & 3) + 8 * (reg >> 2);
        int col = ccol0 + n * 32;
        float v = acc[m][n][reg];
        if (MODE == 0) {
          ((float*)C)[row * N + col] = v;
        } else {
          float other = __shfl_xor(v, 1, 64); // col pairs live in adjacent lanes
          float out = v;
          if (col < 5120) { // RoPE on Q and K columns
            int s = (int)(row & 2047);
            int ib = (col & 127) >> 1;
            float cc = cosp[s * 64 + ib], ss = sinp[s * 64 + ib];
            out = (col & 1) ? (other * ss + v * cc) : (v * cc - other * ss);
            if (col < 4096) out *= qscale; // 1/sqrt(128)*log2e folded into Q
          }
          ((unsigned short*)C)[row * N + col] = f2b_rne(out);
        }
      }
}

// ---------- flash attention, causal, GQA(4:1), XOR-swizzled LDS (40KB -> 4 blocks/CU) ----------
// XCD-aware block map: bid&7 = kh, so all blocks sharing a K/V stream land on one XCD.
// Work-balanced: each block handles q-tiles (qt, nqt-1-qt) -> uniform nqt+1 kv-tiles.
// NO min-blocks bound: R12 showed (256,4) caps VGPR at 64 -> scratch spills -> 755MB HBM.
__global__ __launch_bounds__(256) void attn_kernel(const unsigned short* __restrict__ QKV,
                                                   const unsigned short* __restrict__ Vt,
                                                   unsigned short* __restrict__ O,
                                                   int S, int BS) {
  __shared__ unsigned short Ks[64 * 128];   // [kv][d], chunk^=(kv&7)
  __shared__ unsigned short Vs[128 * 64];   // [d][kv], chunk^=(d&7)
  __shared__ unsigned short Ps[4][16 * 64]; // per-wave [q][kv], chunk^=(q&7)
  const int tid = threadIdx.x, wave = tid >> 6, lane = tid & 63;
  const int lrow = lane & 15, kgrp = lane >> 4;
  const int nqt = S >> 6, nqt2 = nqt >> 1; // nqt2 = 16 for S=2048
  // decode XCD-grouped bid: bid = kh + 8*(qp + nqt2*(h2 + 4*b))
  int bid = blockIdx.x;
  const int kh = bid & 7; bid >>= 3;
  const int qp = bid % nqt2; bid /= nqt2;
  const int h2 = bid & 3;
  const int b = bid >> 2;
  const int h = kh * 4 + h2;
  const long rowbase = (long)b * S;

  const char* kg = (const char*)(QKV + rowbase * 6144 + 4096 + kh * 128)
                   + (tid >> 4) * 12288 + (((tid & 15) ^ ((tid >> 4) & 7)) * 16);
  const char* vg = (const char*)(Vt + (long)(kh * 128 + (tid >> 3)) * BS + rowbase)
                   + (((tid & 7) ^ ((tid >> 3) & 7)) * 16);
  char* lK = (char*)Ks + wave * 1024;
  char* lV = (char*)Vs + wave * 1024;

  for (int pass = 0; pass < 2; pass++) {
    const int qt = pass ? (nqt - 1 - qp) : qp;
    const int qbase = qt * 64;
    const int q0 = qbase + wave * 16;

    short8 qf[4];
    {
      const unsigned short* qpt = QKV + (rowbase + q0 + lrow) * 6144 + h * 128 + kgrp * 8;
#pragma unroll
      for (int dc = 0; dc < 4; dc++) qf[dc] = *(const short8*)(qpt + dc * 32);
    }
    f32x4 oacc[8];
#pragma unroll
    for (int dt = 0; dt < 8; dt++) oacc[dt] = (f32x4){0.f, 0.f, 0.f, 0.f};
    float mrun[4] = {-1e30f, -1e30f, -1e30f, -1e30f};
    float lrun[4] = {0.f, 0.f, 0.f, 0.f};

    const int kv_end = qbase + 64;
    for (int kv0 = 0; kv0 < kv_end; kv0 += 64) {
      __syncthreads();
#pragma unroll
      for (int p = 0; p < 4; p++)
        GL16(kg + (long)(kv0 + p * 16) * 12288, lK + p * 4096);
#pragma unroll
      for (int p = 0; p < 4; p++)
        GL16(vg + (long)kv0 * 2 + (long)p * 32 * BS * 2, lV + p * 4096);
      __syncthreads();

      f32x4 sc[4];
#pragma unroll
      for (int n = 0; n < 4; n++) {
        f32x4 s = (f32x4){0.f, 0.f, 0.f, 0.f};
#pragma unroll
        for (int dc = 0; dc < 4; dc++) {
          short8 kf = *(const short8*)(Ks + (n * 16 + lrow) * 128 + (((dc * 4 + kgrp) ^ (lrow & 7)) << 3));
          s = __builtin_amdgcn_mfma_f32_16x16x32_bf16(qf[dc], kf, s, 0, 0, 0);
        }
        sc[n] = s;
      }

      if (kv0 + 63 > q0) { // diagonal tile: causal mask
#pragma unroll
        for (int r = 0; r < 4; r++) {
          const int qg = q0 + kgrp * 4 + r;
#pragma unroll
          for (int n = 0; n < 4; n++) {
            int kgi = kv0 + n * 16 + lrow;
            if (kgi > qg) sc[n][r] = -1e30f;
          }
        }
      }

      float mx[4];
#pragma unroll
      for (int r = 0; r < 4; r++) {
        float m0 = fmaxf(fmaxf(sc[0][r], sc[1][r]), fmaxf(sc[2][r], sc[3][r]));
#pragma unroll
        for (int d = 1; d < 16; d <<= 1) m0 = fmaxf(m0, __shfl_xor(m0, d, 64));
        mx[r] = m0;
      }
      bool grow = false;
#pragma unroll
      for (int r = 0; r < 4; r++) grow = grow || (mx[r] > mrun[r] + 8.f);

      if (__all(!grow)) {
#pragma unroll
        for (int r = 0; r < 4; r++) {
          const int q = kgrp * 4 + r;
          const int pbase = q * 64;
          float psum = 0.f;
#pragma unroll
          for (int n = 0; n < 4; n++) {
            float pv = EXP2F(sc[n][r] - mrun[r]);
            psum += pv;
            int k = n * 16 + lrow;
            Ps[wave][pbase + ((((k >> 3) ^ (q & 7)) << 3) | (k & 7))] = f2b_rne(pv);
          }
          lrun[r] += psum;
        }
      } else {
#pragma unroll
        for (int r = 0; r < 4; r++) {
          const int q = kgrp * 4 + r;
          const int pbase = q * 64;
          float mnew = fmaxf(mrun[r], mx[r]);
          float corr = EXP2F(mrun[r] - mnew);
          mrun[r] = mnew;
          float psum = 0.f;
#pragma unroll
          for (int n = 0; n < 4; n++) {
            float pv = EXP2F(sc[n][r] - mnew);
            psum += pv;
            int k = n * 16 + lrow;
            Ps[wave][pbase + ((((k >> 3) ^ (q & 7)) << 3) | (k & 7))] = f2b_rne(pv);
          }
          lrun[r] = lrun[r] * corr + psum;
#pragma unroll
          for (int dt = 0; dt < 8; dt++) oacc[dt][r] *= corr;
        }
      }
      asm volatile("s_waitcnt lgkmcnt(0)" ::: "memory");
#pragma unroll
      for (int kc = 0; kc < 2; kc++) {
        short8 pa = *(const short8*)(&Ps[wave][lrow * 64 + (((kc * 4 + kgrp) ^ (lrow & 7)) << 3)]);
#pragma unroll
        for (int dt = 0; dt < 8; dt++) {
          short8 vb = *(const short8*)(Vs + (dt * 16 + lrow) * 64 + (((kc * 4 + kgrp) ^ (lrow & 7)) << 3));
          oacc[dt] = __builtin_amdgcn_mfma_f32_16x16x32_bf16(pa, vb, oacc[dt], 0, 0, 0);
        }
      }
    }

    float inv[4];
#pragma unroll
    for (int r = 0; r < 4; r++) {
      float l = lrun[r];
#pragma unroll
      for (int d = 1; d < 16; d <<= 1) l += __shfl_xor(l, d, 64);
      inv[r] = 1.f / l;
    }
    unsigned short* op = O + (rowbase + q0 + kgrp * 4) * 4096 + h * 128 + lrow;
#pragma unroll
    for (int dt = 0; dt < 8; dt++)
#pragma unroll
      for (int r = 0; r < 4; r++)
        op[(long)r * 4096 + dt * 16] = f2b_rne(oacc[dt][r] * inv[r]);
  }
}

extern "C" void kernel_launch(void* const* d_in, const int* in_sizes, int n_in,
                              void* d_out, int out_size, void* d_ws, size_t ws_size,
                              hipStream_t stream) {
  const float* x = (const float*)d_in[0];
  const float* cosp = (const float*)d_in[1];
  const float* sinp = (const float*)d_in[2];
  // d_in[3] = mask (causal 0/-1e9) -- applied analytically
  const float* Wq = (const float*)d_in[4];
  const float* Wk = (const float*)d_in[5];
  const float* Wv = (const float*)d_in[6];
  const float* Wo = (const float*)d_in[7];
  const int S = 2048;
  const long M = 4096; // B*S

  if (ws_size < 176160768ULL) return; // need 168 MiB scratch

  char* ws = (char*)d_ws;
  unsigned short* xb   = (unsigned short*)(ws);               // 32 MiB (aliased as AO later)
  unsigned short* Wqt  = (unsigned short*)(ws + 33554432);    // 48 MiB: Wqt|Wkt|Wvt = [6144][4096]
  unsigned short* Wot  = (unsigned short*)(ws + 83886080);    // 32 MiB
  unsigned short* QKVb = (unsigned short*)(ws + 117440512);   // 48 MiB [4096][6144]
  unsigned short* Vtg  = (unsigned short*)(ws + 167772160);   //  8 MiB [1024][4096]
  unsigned short* AO   = xb; // xb dead after QKV GEMM

  conv_f32_bf16<<<16384, 256, 0, stream>>>(x, xb, M * 4096);
  prep_weights<<<40960, 256, 0, stream>>>(Wq, Wk, Wv, Wo, Wqt, Wot);

  // fused QKV projection + RoPE epilogue: Bt = [Wqt|Wkt|Wvt], C = QKVb (4096 x 6144)
  gemm_m97<2, 3><<<1536, 256, 0, stream>>>(xb, Wqt, QKVb, cosp, sinp, 4096, 6144, 4096);
  // V^T for attention PV: from QKV cols 5120..6143 (un-roped)
  transpose_u16<<<dim3(32, 128), 256, 0, stream>>>(QKVb + 5120, Vtg, 4096, 1024, 6144);

  attn_kernel<<<1024, 256, 0, stream>>>(QKVb, Vtg, AO, S, 4096);

  gemm_m97<0, 4><<<1024, 256, 0, stream>>>(AO, Wot, d_out, nullptr, nullptr, 4096, 4096, 4096);
}

// Round 14
// 645.415 us; speedup vs baseline: 1.2279x; 1.1539x over previous
//
#include <hip/hip_runtime.h>

typedef __attribute__((ext_vector_type(8))) short short8;
typedef __attribute__((ext_vector_type(4))) float f32x4;
typedef __attribute__((ext_vector_type(16))) float f32x16;
typedef __attribute__((ext_vector_type(4))) unsigned short u16x4;
typedef __attribute__((ext_vector_type(8))) unsigned short u16x8;

typedef __attribute__((address_space(3))) void lds_void;
typedef __attribute__((address_space(1))) void g_void;

#define GL16(g, l) __builtin_amdgcn_global_load_lds((g_void*)(g), (lds_void*)(l), 16, 0, 0)
#define EXP2F(x) __builtin_exp2f(x)

__device__ inline float b2f(unsigned short u) {
  union { unsigned u; float f; } v; v.u = ((unsigned)u) << 16; return v.f;
}
__device__ inline unsigned short f2b(float f) {
  union { float f; unsigned u; } v; v.f = f;
  unsigned r = v.u + 0x7FFFu + ((v.u >> 16) & 1u);
  return (unsigned short)(r >> 16);
}
__device__ inline unsigned short f2b_rne(float f) {
  unsigned u;
  asm("v_cvt_pk_bf16_f32 %0, %1, %2" : "=v"(u) : "v"(f), "v"(f));
  return (unsigned short)u;
}

// ---------- fp32 -> bf16 convert (vectorized) ----------
__global__ __launch_bounds__(256) void conv_f32_bf16(const float* __restrict__ in,
                                                     unsigned short* __restrict__ out, long n) {
  long i = ((long)blockIdx.x * 256 + threadIdx.x) * 4;
  if (i >= n) return;
  f32x4 v = *(const f32x4*)(in + i);
  u16x4 o;
  o[0] = f2b(v[0]); o[1] = f2b(v[1]); o[2] = f2b(v[2]); o[3] = f2b(v[3]);
  *(u16x4*)(out + i) = o;
}

// ---------- all 4 weight transposes in one launch: W (4096 x C) -> W^T bf16 (C x 4096) ----------
__global__ __launch_bounds__(256) void prep_weights(const float* __restrict__ Wq,
                                                    const float* __restrict__ Wk,
                                                    const float* __restrict__ Wv,
                                                    const float* __restrict__ Wo,
                                                    unsigned short* __restrict__ Wqkv,
                                                    unsigned short* __restrict__ Wot) {
  __shared__ unsigned short tile[32][33];
  int id = blockIdx.x;
  const float* src; unsigned short* dst; int C;
  if (id < 16384)      { src = Wq; dst = Wqkv;            C = 4096; }
  else if (id < 20480) { src = Wk; dst = Wqkv + 16777216; C = 1024; id -= 16384; }
  else if (id < 24576) { src = Wv; dst = Wqkv + 20971520; C = 1024; id -= 20480; }
  else                 { src = Wo; dst = Wot;             C = 4096; id -= 24576; }
  const int nbx = C >> 5;
  const int c0 = (id % nbx) * 32, r0 = (id / nbx) * 32;
  const int tx = threadIdx.x & 31, ty = threadIdx.x >> 5;
#pragma unroll
  for (int i = ty; i < 32; i += 8)
    tile[i][tx] = f2b(src[(long)(r0 + i) * C + c0 + tx]);
  __syncthreads();
#pragma unroll
  for (int i = ty; i < 32; i += 8)
    dst[(long)(c0 + i) * 4096 + r0 + tx] = tile[tx][i];
}

// ---------- bf16 transpose for V^T ----------
__global__ __launch_bounds__(256) void transpose_u16(const unsigned short* __restrict__ in,
                                                     unsigned short* __restrict__ out,
                                                     int R, int C, int ldin) {
  __shared__ unsigned short tile[32][33];
  int c0 = blockIdx.x * 32, r0 = blockIdx.y * 32;
  int tx = threadIdx.x & 31, ty = threadIdx.x >> 5;
#pragma unroll
  for (int i = ty; i < 32; i += 8)
    tile[i][tx] = in[(long)(r0 + i) * ldin + c0 + tx];
  __syncthreads();
#pragma unroll
  for (int i = ty; i < 32; i += 8)
    out[(long)(c0 + i) * R + r0 + tx] = tile[tx][i];
}

// ---------- bf16 GEMM, m97 structure, 128x128 tile, BK=64, 32x32x16 MFMA ----------
// MODE 0: fp32 C. MODE 2: bf16 C with fused RoPE on cols<5120 (qscale on cols<4096).
template <int MODE, int MINB>
__global__ __launch_bounds__(256, MINB) void gemm_m97(const unsigned short* __restrict__ A,
                                                      const unsigned short* __restrict__ Bt,
                                                      void* __restrict__ C,
                                                      const float* __restrict__ cosp,
                                                      const float* __restrict__ sinp,
                                                      int M, int N, int K) {
  __shared__ unsigned short As[128 * 64];
  __shared__ unsigned short Bs[128 * 64];
  const int tid = threadIdx.x;
  const int lane = tid & 63;
  const int wid = tid >> 6;
  const int wr = wid >> 1, wc = wid & 1;         // 2x2 waves, wave tile 64x64
  const int l31 = lane & 31, lh = lane >> 5;
  const int xr = l31 & 7;
  const int nbn = N >> 7;
  const int bm = blockIdx.x / nbn, bn = blockIdx.x % nbn; // natural order (L2-friendly)

  const long K2 = (long)K * 2;
  const int csw = ((tid & 7) ^ ((tid >> 3) & 7)) << 4;
  const char* gA = (const char*)A + ((long)bm * 128 + (tid >> 3)) * K2 + csw;
  const char* gB = (const char*)Bt + ((long)bn * 128 + (tid >> 3)) * K2 + csw;
  char* dA = (char*)As + tid * 16;
  char* dB = (char*)Bs + tid * 16;

  f32x16 acc[2][2];
#pragma unroll
  for (int m = 0; m < 2; m++)
#pragma unroll
    for (int n = 0; n < 2; n++)
#pragma unroll
      for (int i = 0; i < 16; i++) acc[m][n][i] = 0.f;

  const int offA0 = (wr * 64 + l31) * 128;
  const int offB0 = (wc * 64 + l31) * 128;

  const int NT = K >> 6;
  for (int t = 0; t < NT; ++t) {
    __syncthreads();
    const long ko = (long)t * 128;
    GL16(gA + ko, dA);
    GL16(gA + ko + 32 * K2, dA + 4096);
    GL16(gA + ko + 64 * K2, dA + 8192);
    GL16(gA + ko + 96 * K2, dA + 12288);
    GL16(gB + ko, dB);
    GL16(gB + ko + 32 * K2, dB + 4096);
    GL16(gB + ko + 64 * K2, dB + 8192);
    GL16(gB + ko + 96 * K2, dB + 12288);
    __syncthreads();
#pragma unroll
    for (int kk = 0; kk < 4; kk++) {
      const int co = (((kk * 2 + lh) ^ xr) << 4);
      short8 a0 = *(const short8*)((const char*)As + offA0 + co);
      short8 a1 = *(const short8*)((const char*)As + offA0 + 4096 + co);
      short8 b0 = *(const short8*)((const char*)Bs + offB0 + co);
      short8 b1 = *(const short8*)((const char*)Bs + offB0 + 4096 + co);
      acc[0][0] = __builtin_amdgcn_mfma_f32_32x32x16_bf16(a0, b0, acc[0][0], 0, 0, 0);
      acc[0][1] = __builtin_amdgcn_mfma_f32_32x32x16_bf16(a0, b1, acc[0][1], 0, 0, 0);
      acc[1][0] = __builtin_amdgcn_mfma_f32_32x32x16_bf16(a1, b0, acc[1][0], 0, 0, 0);
      acc[1][1] = __builtin_amdgcn_mfma_f32_32x32x16_bf16(a1, b1, acc[1][1], 0, 0, 0);
    }
  }

  const long crow0 = (long)bm * 128 + wr * 64 + 4 * lh;
  const int ccol0 = bn * 128 + wc * 64 + l31;
  const float qscale = 0.08838834764831845f * 1.44269504088896341f;
#pragma unroll
  for (int m = 0; m < 2; m++)
#pragma unroll
    for (int n = 0; n < 2; n++)
#pragma unroll
      for (int reg = 0; reg < 16; reg++) {
        long row = crow0 + m * 32 + (reg & 3) + 8 * (reg >> 2);
        int col = ccol0 + n * 32;
        float v = acc[m][n][reg];
        if (MODE == 0) {
          ((float*)C)[row * N + col] = v;
        } else {
          float other = __shfl_xor(v, 1, 64); // col pairs live in adjacent lanes
          float out = v;
          if (col < 5120) { // RoPE on Q and K columns
            int s = (int)(row & 2047);
            int ib = (col & 127) >> 1;
            float cc = cosp[s * 64 + ib], ss = sinp[s * 64 + ib];
            out = (col & 1) ? (other * ss + v * cc) : (v * cc - other * ss);
            if (col < 4096) out *= qscale; // 1/sqrt(128)*log2e folded into Q
          }
          ((unsigned short*)C)[row * N + col] = f2b_rne(out);
        }
      }
}

// ---------- flash attention, causal, GQA(4:1) ----------
// R10-exact body (pad-68 Ps, VGPR ~96, no launch bound) + XCD-grouped bid decode
// (kh = bid&7: cuts FETCH 77->25MB). R11-R13 lesson: swizzled-Ps index math pushed
// VGPR past the 128 cliff (96->136), halving occupancy for zero conflict benefit.
__global__ __launch_bounds__(256) void attn_kernel(const unsigned short* __restrict__ QKV,
                                                   const unsigned short* __restrict__ Vt,
                                                   unsigned short* __restrict__ O,
                                                   int S, int BS) {
  __shared__ unsigned short Ks[64 * 128];   // [kv][d], chunk^=(kv&7)
  __shared__ unsigned short Vs[128 * 64];   // [d][kv], chunk^=(d&7)
  __shared__ unsigned short Ps[4][16 * 68]; // per-wave [q][kv], pad 68
  const int tid = threadIdx.x, wave = tid >> 6, lane = tid & 63;
  const int lrow = lane & 15, kgrp = lane >> 4;
  const int nqt = S >> 6, nqt2 = nqt >> 1; // nqt2 = 16 for S=2048
  // XCD-grouped decode: bid = kh + 8*(qp + nqt2*(h2 + 4*b))
  int bid = blockIdx.x;
  const int kh = bid & 7; bid >>= 3;
  const int qp = bid % nqt2; bid /= nqt2;
  const int h2 = bid & 3;
  const int b = bid >> 2;
  const int h = kh * 4 + h2;
  const long rowbase = (long)b * S;

  const char* kg = (const char*)(QKV + rowbase * 6144 + 4096 + kh * 128)
                   + (tid >> 4) * 12288 + (((tid & 15) ^ ((tid >> 4) & 7)) * 16);
  const char* vg = (const char*)(Vt + (long)(kh * 128 + (tid >> 3)) * BS + rowbase)
                   + (((tid & 7) ^ ((tid >> 3) & 7)) * 16);
  char* lK = (char*)Ks + wave * 1024;
  char* lV = (char*)Vs + wave * 1024;

  for (int pass = 0; pass < 2; pass++) {
    const int qt = pass ? (nqt - 1 - qp) : qp;
    const int qbase = qt * 64;
    const int q0 = qbase + wave * 16;

    short8 qf[4];
    {
      const unsigned short* qpt = QKV + (rowbase + q0 + lrow) * 6144 + h * 128 + kgrp * 8;
#pragma unroll
      for (int dc = 0; dc < 4; dc++) qf[dc] = *(const short8*)(qpt + dc * 32);
    }
    f32x4 oacc[8];
#pragma unroll
    for (int dt = 0; dt < 8; dt++) oacc[dt] = (f32x4){0.f, 0.f, 0.f, 0.f};
    float mrun[4] = {-1e30f, -1e30f, -1e30f, -1e30f};
    float lrun[4] = {0.f, 0.f, 0.f, 0.f};

    const int kv_end = qbase + 64;
    for (int kv0 = 0; kv0 < kv_end; kv0 += 64) {
      __syncthreads();
#pragma unroll
      for (int p = 0; p < 4; p++)
        GL16(kg + (long)(kv0 + p * 16) * 12288, lK + p * 4096);
#pragma unroll
      for (int p = 0; p < 4; p++)
        GL16(vg + (long)kv0 * 2 + (long)p * 32 * BS * 2, lV + p * 4096);
      __syncthreads();

      f32x4 sc[4];
#pragma unroll
      for (int n = 0; n < 4; n++) {
        f32x4 s = (f32x4){0.f, 0.f, 0.f, 0.f};
#pragma unroll
        for (int dc = 0; dc < 4; dc++) {
          short8 kf = *(const short8*)(Ks + (n * 16 + lrow) * 128 + (((dc * 4 + kgrp) ^ (lrow & 7)) << 3));
          s = __builtin_amdgcn_mfma_f32_16x16x32_bf16(qf[dc], kf, s, 0, 0, 0);
        }
        sc[n] = s;
      }

      if (kv0 + 63 > q0) { // diagonal tile: causal mask
#pragma unroll
        for (int r = 0; r < 4; r++) {
          const int qg = q0 + kgrp * 4 + r;
#pragma unroll
          for (int n = 0; n < 4; n++) {
            int kgi = kv0 + n * 16 + lrow;
            if (kgi > qg) sc[n][r] = -1e30f;
          }
        }
      }

      float mx[4];
#pragma unroll
      for (int r = 0; r < 4; r++) {
        float m0 = fmaxf(fmaxf(sc[0][r], sc[1][r]), fmaxf(sc[2][r], sc[3][r]));
#pragma unroll
        for (int d = 1; d < 16; d <<= 1) m0 = fmaxf(m0, __shfl_xor(m0, d, 64));
        mx[r] = m0;
      }
      bool grow = false;
#pragma unroll
      for (int r = 0; r < 4; r++) grow = grow || (mx[r] > mrun[r] + 8.f);

      if (__all(!grow)) {
#pragma unroll
        for (int r = 0; r < 4; r++) {
          float psum = 0.f;
#pragma unroll
          for (int n = 0; n < 4; n++) {
            float pv = EXP2F(sc[n][r] - mrun[r]);
            psum += pv;
            Ps[wave][(kgrp * 4 + r) * 68 + n * 16 + lrow] = f2b_rne(pv);
          }
          lrun[r] += psum;
        }
      } else {
#pragma unroll
        for (int r = 0; r < 4; r++) {
          float mnew = fmaxf(mrun[r], mx[r]);
          float corr = EXP2F(mrun[r] - mnew);
          mrun[r] = mnew;
          float psum = 0.f;
#pragma unroll
          for (int n = 0; n < 4; n++) {
            float pv = EXP2F(sc[n][r] - mnew);
            psum += pv;
            Ps[wave][(kgrp * 4 + r) * 68 + n * 16 + lrow] = f2b_rne(pv);
          }
          lrun[r] = lrun[r] * corr + psum;
#pragma unroll
          for (int dt = 0; dt < 8; dt++) oacc[dt][r] *= corr;
        }
      }
      asm volatile("s_waitcnt lgkmcnt(0)" ::: "memory");
#pragma unroll
      for (int kc = 0; kc < 2; kc++) {
        short8 pa = *(const short8*)(&Ps[wave][lrow * 68 + kc * 32 + kgrp * 8]);
#pragma unroll
        for (int dt = 0; dt < 8; dt++) {
          short8 vb = *(const short8*)(Vs + (dt * 16 + lrow) * 64 + (((kc * 4 + kgrp) ^ (lrow & 7)) << 3));
          oacc[dt] = __builtin_amdgcn_mfma_f32_16x16x32_bf16(pa, vb, oacc[dt], 0, 0, 0);
        }
      }
    }

    float inv[4];
#pragma unroll
    for (int r = 0; r < 4; r++) {
      float l = lrun[r];
#pragma unroll
      for (int d = 1; d < 16; d <<= 1) l += __shfl_xor(l, d, 64);
      inv[r] = 1.f / l;
    }
    unsigned short* op = O + (rowbase + q0 + kgrp * 4) * 4096 + h * 128 + lrow;
#pragma unroll
    for (int dt = 0; dt < 8; dt++)
#pragma unroll
      for (int r = 0; r < 4; r++)
        op[(long)r * 4096 + dt * 16] = f2b_rne(oacc[dt][r] * inv[r]);
  }
}

extern "C" void kernel_launch(void* const* d_in, const int* in_sizes, int n_in,
                              void* d_out, int out_size, void* d_ws, size_t ws_size,
                              hipStream_t stream) {
  const float* x = (const float*)d_in[0];
  const float* cosp = (const float*)d_in[1];
  const float* sinp = (const float*)d_in[2];
  // d_in[3] = mask (causal 0/-1e9) -- applied analytically
  const float* Wq = (const float*)d_in[4];
  const float* Wk = (const float*)d_in[5];
  const float* Wv = (const float*)d_in[6];
  const float* Wo = (const float*)d_in[7];
  const int S = 2048;
  const long M = 4096; // B*S

  if (ws_size < 176160768ULL) return; // need 168 MiB scratch

  char* ws = (char*)d_ws;
  unsigned short* xb   = (unsigned short*)(ws);               // 32 MiB (aliased as AO later)
  unsigned short* Wqt  = (unsigned short*)(ws + 33554432);    // 48 MiB: Wqt|Wkt|Wvt = [6144][4096]
  unsigned short* Wot  = (unsigned short*)(ws + 83886080);    // 32 MiB
  unsigned short* QKVb = (unsigned short*)(ws + 117440512);   // 48 MiB [4096][6144]
  unsigned short* Vtg  = (unsigned short*)(ws + 167772160);   //  8 MiB [1024][4096]
  unsigned short* AO   = xb; // xb dead after QKV GEMM

  conv_f32_bf16<<<16384, 256, 0, stream>>>(x, xb, M * 4096);
  prep_weights<<<40960, 256, 0, stream>>>(Wq, Wk, Wv, Wo, Wqt, Wot);

  // fused QKV projection + RoPE epilogue: Bt = [Wqt|Wkt|Wvt], C = QKVb (4096 x 6144)
  gemm_m97<2, 3><<<1536, 256, 0, stream>>>(xb, Wqt, QKVb, cosp, sinp, 4096, 6144, 4096);
  // V^T for attention PV: from QKV cols 5120..6143 (un-roped)
  transpose_u16<<<dim3(32, 128), 256, 0, stream>>>(QKVb + 5120, Vtg, 4096, 1024, 6144);

  attn_kernel<<<1024, 256, 0, stream>>>(QKVb, Vtg, AO, S, 4096);

  gemm_m97<0, 4><<<1024, 256, 0, stream>>>(AO, Wot, d_out, nullptr, nullptr, 4096, 4096, 4096);
}